// Round 8
// baseline (1571.867 us; speedup 1.0000x reference)
//
#include <hip/hip_runtime.h>

// ---- problem constants ----
#define B_ 8
#define T_ 1024
#define C_ 384
#define L_ 8
#define H_ 16
#define D_ 24
#define F_ 1536
#define M_ 8192   // B_*T_

using bf16x8 = __attribute__((ext_vector_type(8))) __bf16;
using f32x4  = __attribute__((ext_vector_type(4))) float;

__device__ __forceinline__ ushort f2b(float f) {
  union { float f; unsigned u; } cv; cv.f = f;
  unsigned u = cv.u;
  return (ushort)((u + 0x7FFFu + ((u >> 16) & 1u)) >> 16);  // RNE
}
__device__ __forceinline__ ushort f2b_cvt(float f) {  // 1-inst HW cvt (RNE)
  __bf16 h = (__bf16)f;
  return *(ushort*)&h;
}
__device__ __forceinline__ void gload_lds16(const void* g, void* l) {
  __builtin_amdgcn_global_load_lds((const __attribute__((address_space(1))) void*)g,
                                   (__attribute__((address_space(3))) void*)l, 16, 0, 0);
}

// Q pre-scale: 24^-0.5 * log2(e)  (softmax exp becomes bare exp2)
#define QSCL 0.29448870f

// ---------------- embed: x = idx + pos ----------------
__global__ __launch_bounds__(256) void k_embed(const float* __restrict__ idx,
                                               const float* __restrict__ pos,
                                               float* __restrict__ x) {
  long i4 = ((long)blockIdx.x * 256 + threadIdx.x) * 4;
  float4 a = *(const float4*)(idx + i4);
  long p = i4 % (long)(T_ * C_);
  float4 b = *(const float4*)(pos + p);
  a.x += b.x; a.y += b.y; a.z += b.z; a.w += b.w;
  *(float4*)(x + i4) = a;
}

// ---------------- layernorm (fp32 in) -> bf16 out ----------------
__global__ __launch_bounds__(256) void k_ln(const float* __restrict__ x,
                                            const float* __restrict__ g,
                                            const float* __restrict__ b,
                                            ushort* __restrict__ out) {
  int row  = blockIdx.x * 4 + (threadIdx.x >> 6);
  int lane = threadIdx.x & 63;
  const float* xr = x + (long)row * C_;
  float v[6]; float sum = 0.f;
#pragma unroll
  for (int i = 0; i < 3; ++i) {
    float2 t = *(const float2*)(xr + 2*(lane + 64*i));
    v[2*i] = t.x; v[2*i+1] = t.y; sum += t.x + t.y;
  }
#pragma unroll
  for (int m = 1; m < 64; m <<= 1) sum += __shfl_xor(sum, m);
  float mean = sum * (1.f / C_);
  float vs = 0.f;
#pragma unroll
  for (int i = 0; i < 6; ++i) { float d = v[i] - mean; vs += d * d; }
#pragma unroll
  for (int m = 1; m < 64; m <<= 1) vs += __shfl_xor(vs, m);
  float rstd = rsqrtf(vs * (1.f / C_) + 1e-5f);
  ushort* orow = out + (long)row * C_;
#pragma unroll
  for (int i = 0; i < 3; ++i) {
    int c = 2*(lane + 64*i);
    float2 gg = *(const float2*)(g + c);
    float2 bb = *(const float2*)(b + c);
    ushort2 w;
    w.x = f2b((v[2*i]   - mean) * rstd * gg.x + bb.x);
    w.y = f2b((v[2*i+1] - mean) * rstd * gg.y + bb.y);
    *(ushort2*)(orow + c) = w;
  }
}

// ---------------- final layernorm + relu -> fp32 d_out ----------------
__global__ __launch_bounds__(256) void k_lnf(const float* __restrict__ x,
                                             const float* __restrict__ g,
                                             const float* __restrict__ b,
                                             float* __restrict__ out) {
  int row  = blockIdx.x * 4 + (threadIdx.x >> 6);
  int lane = threadIdx.x & 63;
  const float* xr = x + (long)row * C_;
  float v[6]; float sum = 0.f;
#pragma unroll
  for (int i = 0; i < 3; ++i) {
    float2 t = *(const float2*)(xr + 2*(lane + 64*i));
    v[2*i] = t.x; v[2*i+1] = t.y; sum += t.x + t.y;
  }
#pragma unroll
  for (int m = 1; m < 64; m <<= 1) sum += __shfl_xor(sum, m);
  float mean = sum * (1.f / C_);
  float vs = 0.f;
#pragma unroll
  for (int i = 0; i < 6; ++i) { float d = v[i] - mean; vs += d * d; }
#pragma unroll
  for (int m = 1; m < 64; m <<= 1) vs += __shfl_xor(vs, m);
  float rstd = rsqrtf(vs * (1.f / C_) + 1e-5f);
  float* orow = out + (long)row * C_;
#pragma unroll
  for (int i = 0; i < 3; ++i) {
    int c = 2*(lane + 64*i);
    float2 gg = *(const float2*)(g + c);
    float2 bb = *(const float2*)(b + c);
    float2 w;
    w.x = fmaxf((v[2*i]   - mean) * rstd * gg.x + bb.x, 0.f);
    w.y = fmaxf((v[2*i+1] - mean) * rstd * gg.y + bb.y, 0.f);
    *(float2*)(orow + c) = w;
  }
}

// ---------------- weight transpose+cast kernels ----------------
__global__ __launch_bounds__(256) void k_trans_qkv(const float* __restrict__ src,
                                                   ushort* __restrict__ dst, int which) {
  __shared__ float tile[32][33];
  int z = blockIdx.z;            // l*H + h
  int l = z >> 4, hh = z & 15;
  const float* sb = src + (long)z * C_ * D_;
  ushort* db = dst + (long)l * (3*C_) * C_ + (long)(which * C_ + hh * D_) * C_;
  int r0 = blockIdx.y * 32;      // c dim
  int tx = threadIdx.x & 31, ty = threadIdx.x >> 5;
#pragma unroll
  for (int i = 0; i < 32; i += 8)
    tile[ty + i][tx] = (tx < D_) ? sb[(long)(r0 + ty + i) * D_ + tx] : 0.f;
  __syncthreads();
#pragma unroll
  for (int i = 0; i < 32; i += 8) {
    int s = ty + i, r = r0 + tx;
    if (s < D_) db[(long)s * C_ + r] = f2b(tile[tx][ty + i]);
  }
}

__global__ __launch_bounds__(256) void k_trans_w(const float* __restrict__ src,
                                                 ushort* __restrict__ dst, int R, int S) {
  __shared__ float tile[32][33];
  const float* sb = src + (long)blockIdx.z * R * S;
  ushort* db = dst + (long)blockIdx.z * R * S;
  int r0 = blockIdx.y * 32, s0 = blockIdx.x * 32;
  int tx = threadIdx.x & 31, ty = threadIdx.x >> 5;
#pragma unroll
  for (int i = 0; i < 32; i += 8) {
    int r = r0 + ty + i, s = s0 + tx;
    tile[ty + i][tx] = (r < R && s < S) ? sb[(long)r * S + s] : 0.f;
  }
  __syncthreads();
#pragma unroll
  for (int i = 0; i < 32; i += 8) {
    int s = s0 + ty + i, r = r0 + tx;
    if (s < S && r < R) db[(long)s * R + r] = f2b(tile[tx][ty + i]);
  }
}

// ---------------- ones row for Vt (d=24): PV then yields row-sums free ----
__global__ __launch_bounds__(256) void k_ones(ushort* __restrict__ Vt) {
  ushort4 one4 = {0x3F80, 0x3F80, 0x3F80, 0x3F80};
  *(ushort4*)(Vt + ((long)blockIdx.x * 32 + 24) * 1024 + threadIdx.x * 4) = one4;
}

// ---------------- GEMM: A[M,K]bf16 @ Bt[N,K]^T -> out[M,N] ----------------
// 128xBN tile, BK=64, 4 waves, mfma 16x16x32, global_load_lds(16B) with
// pre-swizzled SOURCE + XOR-swizzled READ (rule 21: linear LDS dest).
// QKV mode (qp!=null): epilogue scatters Q (pre-scaled by QSCL) ->Qp[bh][t][32],
// K->Kp[bh][s][32], V->Vt[bh][d][1024]; pads pre-zeroed, Vt row24 = ones.
template<int BN>
__global__ __launch_bounds__(256) void k_gemm(const ushort* __restrict__ A, int lda,
                                              const ushort* __restrict__ Bt, int ldb,
                                              const float* __restrict__ bias,
                                              const float* resid,
                                              float* outF, ushort* outB,
                                              ushort* qp, ushort* kp, ushort* vt,
                                              int N, int K, int relu) {
  __shared__ ushort As[128 * 64];
  __shared__ ushort Bs[BN * 64];
  constexpr int ITB = BN / 32;                 // B-tile gload iters per thread
  constexpr int MF  = (BN == 128) ? 4 : 2;     // row-fragments per wave
  int m0 = blockIdx.y * 128, n0 = blockIdx.x * BN;
  int tid = threadIdx.x, lane = tid & 63, wid = tid >> 6;
  int wr = (BN == 128) ? (wid >> 1) * 64 : wid * 32;
  int wc = (BN == 128) ? (wid & 1) * 64 : 0;
  int g = lane >> 4, q = lane & 15;
  f32x4 acc[MF][4] = {};

  for (int k0 = 0; k0 < K; k0 += 64) {
    __syncthreads();
#pragma unroll
    for (int it = 0; it < 4; ++it) {
      int idx = tid + it * 256;
      int r = idx >> 3;
      int ch = ((idx & 7) ^ (r & 7)) << 3;    // inverse-swizzled source chunk
      gload_lds16(A + (long)(m0 + r) * lda + k0 + ch,
                  (char*)As + (wid * 64 + it * 256) * 16);
    }
#pragma unroll
    for (int it = 0; it < ITB; ++it) {
      int idx = tid + it * 256;
      int r = idx >> 3;
      int ch = ((idx & 7) ^ (r & 7)) << 3;
      gload_lds16(Bt + (long)(n0 + r) * ldb + k0 + ch,
                  (char*)Bs + (wid * 64 + it * 256) * 16);
    }
    __syncthreads();   // compiler drains vmcnt before s_barrier
#pragma unroll
    for (int kk = 0; kk < 2; ++kk) {
      bf16x8 af[MF], bfr[4];
#pragma unroll
      for (int mi = 0; mi < MF; ++mi) {
        int row = wr + mi * 16 + q;
        int byt = ((row * 64 + kk * 32 + g * 8) * 2) ^ ((row & 7) << 4);
        af[mi] = *(const bf16x8*)((const char*)As + byt);
      }
#pragma unroll
      for (int ni = 0; ni < 4; ++ni) {
        int row = wc + ni * 16 + q;
        int byt = ((row * 64 + kk * 32 + g * 8) * 2) ^ ((row & 7) << 4);
        bfr[ni] = *(const bf16x8*)((const char*)Bs + byt);
      }
#pragma unroll
      for (int mi = 0; mi < MF; ++mi)
#pragma unroll
        for (int ni = 0; ni < 4; ++ni)
          acc[mi][ni] = __builtin_amdgcn_mfma_f32_16x16x32_bf16(af[mi], bfr[ni], acc[mi][ni], 0, 0, 0);
    }
  }
  // epilogue: D layout col=lane&15, row=4*(lane>>4)+j  [m89-verified]
#pragma unroll
  for (int mi = 0; mi < MF; ++mi)
#pragma unroll
    for (int ni = 0; ni < 4; ++ni) {
      int rb = m0 + wr + mi * 16 + g * 4;
      int cc = n0 + wc + ni * 16 + q;
      float bv = bias ? bias[cc] : 0.f;
      float vals[4];
#pragma unroll
      for (int j = 0; j < 4; ++j) {
        float val = acc[mi][ni][j] + bv;
        if (resid) val += resid[(long)(rb + j) * N + cc];
        if (relu)  val = fmaxf(val, 0.f);
        vals[j] = val;
      }
      if (qp) {
        // QKV routing (wave-uniform branch: 16-col windows never straddle 384s)
        int sec = (cc >= 768) ? 2 : ((cc >= 384) ? 1 : 0);
        int col = cc - sec * 384;
        int hd = (col * 43691) >> 20;         // /24
        int dd = col - hd * 24;
        int bb = rb >> 10, tt = rb & 1023;
        int bh = bb * 16 + hd;
        if (sec == 2) {
          ushort4 w4 = { f2b(vals[0]), f2b(vals[1]), f2b(vals[2]), f2b(vals[3]) };
          *(ushort4*)(vt + ((long)bh * 32 + dd) * 1024 + tt) = w4;
        } else {
          float sfac = sec ? 1.f : QSCL;      // pre-scale Q for exp2 softmax
          ushort* dst = (sec ? kp : qp) + ((long)bh * 1024 + tt) * 32 + dd;
#pragma unroll
          for (int j = 0; j < 4; ++j) dst[j * 32] = f2b(vals[j] * sfac);
        }
      } else {
#pragma unroll
        for (int j = 0; j < 4; ++j) {
          long off = (long)(rb + j) * N + cc;
          if (outF) outF[off] = vals[j];
          if (outB) outB[off] = f2b(vals[j]);
        }
      }
    }
}

// ---------------- flash attention v6 ----------------
// Balanced 2-pass blocks: block (bh, by) handles q-tiles by and 15-by -> every
// block does exactly 9 x 128-col tiles (no causal tail imbalance). K register
// prefetch (depth 1); interior tiles unmasked (diagonal tile only is masked);
// Q pre-scaled so p = exp2(sc); row-sum comes free from the ones-row of Vt
// (d=24 -> acc1[q=8]). Barrier-free, per-wave-private P-bounce LDS only.
__global__ __launch_bounds__(256) void k_attn(const ushort* __restrict__ Qp,
                                              const ushort* __restrict__ Kp,
                                              const ushort* __restrict__ Vt,
                                              ushort* __restrict__ o) {
  __shared__ ushort Ps[4][16][136];
  int bh = blockIdx.x, by = blockIdx.y;
  int b = bh >> 4, hh = bh & 15;
  int tid = threadIdx.x, lane = tid & 63, w = tid >> 6;
  int g = lane >> 4, q = lane & 15;
  const f32x4 zf = {0.f, 0.f, 0.f, 0.f};

  const ushort* qb  = Qp + (long)bh * 1024 * 32;
  const ushort* kb_ = Kp + (long)bh * 1024 * 32;
  const ushort* vtb = Vt + (long)bh * 32 * 1024;

#pragma unroll
  for (int pass = 0; pass < 2; ++pass) {
    int t0 = (pass ? (15 - by) : by) * 64;
    int send = t0 + 64;
    int nT = (send + 127) >> 7;

    bf16x8 qa = *(const bf16x8*)(qb + (t0 + w * 16 + q) * 32 + g * 8);
    f32x4 acc0 = zf, acc1 = zf;

    bf16x8 kf[8];
#pragma unroll
    for (int si = 0; si < 8; ++si)
      kf[si] = *(const bf16x8*)(kb_ + (si * 16 + q) * 32 + g * 8);

    // interior tiles: fully below diagonal -> no causal mask needed
    for (int it = 0; it < nT - 1; ++it) {
      int s0 = it << 7;
      f32x4 sc[8];
#pragma unroll
      for (int si = 0; si < 8; ++si)
        sc[si] = __builtin_amdgcn_mfma_f32_16x16x32_bf16(qa, kf[si], zf, 0, 0, 0);
#pragma unroll
      for (int si = 0; si < 8; ++si)      // prefetch next tile's K frags
        kf[si] = *(const bf16x8*)(kb_ + (s0 + 128 + si * 16 + q) * 32 + g * 8);
#pragma unroll
      for (int si = 0; si < 8; ++si)
#pragma unroll
        for (int j = 0; j < 4; ++j)
          Ps[w][g * 4 + j][si * 16 + q] = f2b_cvt(exp2f(sc[si][j]));
#pragma unroll
      for (int kk = 0; kk < 4; ++kk) {
        bf16x8 pa  = *(const bf16x8*)(&Ps[w][q][kk * 32 + g * 8]);
        bf16x8 vb0 = *(const bf16x8*)(vtb + (long)q * 1024 + s0 + kk * 32 + g * 8);
        acc0 = __builtin_amdgcn_mfma_f32_16x16x32_bf16(pa, vb0, acc0, 0, 0, 0);
        bf16x8 vb1 = *(const bf16x8*)(vtb + (long)(16 + q) * 1024 + s0 + kk * 32 + g * 8);
        acc1 = __builtin_amdgcn_mfma_f32_16x16x32_bf16(pa, vb1, acc1, 0, 0, 0);
      }
    }
    // diagonal tile (masked); stale Ps cols beyond siMax*16 are never read
    {
      int s0 = (nT - 1) << 7;
      int rem = send - s0;                 // 64 or 128
      int siMax = rem >> 4, kkMax = rem >> 5;
      f32x4 sc[8];
#pragma unroll
      for (int si = 0; si < 8; ++si)
        if (si < siMax)
          sc[si] = __builtin_amdgcn_mfma_f32_16x16x32_bf16(qa, kf[si], zf, 0, 0, 0);
#pragma unroll
      for (int si = 0; si < 8; ++si)
        if (si < siMax) {
          int s_abs = s0 + si * 16 + q;
#pragma unroll
          for (int j = 0; j < 4; ++j) {
            int t_abs = t0 + w * 16 + g * 4 + j;
            float p = (s_abs <= t_abs) ? exp2f(sc[si][j]) : 0.f;
            Ps[w][g * 4 + j][si * 16 + q] = f2b_cvt(p);
          }
        }
#pragma unroll
      for (int kk = 0; kk < 4; ++kk)
        if (kk < kkMax) {
          bf16x8 pa  = *(const bf16x8*)(&Ps[w][q][kk * 32 + g * 8]);
          bf16x8 vb0 = *(const bf16x8*)(vtb + (long)q * 1024 + s0 + kk * 32 + g * 8);
          acc0 = __builtin_amdgcn_mfma_f32_16x16x32_bf16(pa, vb0, acc0, 0, 0, 0);
          bf16x8 vb1 = *(const bf16x8*)(vtb + (long)(16 + q) * 1024 + s0 + kk * 32 + g * 8);
          acc1 = __builtin_amdgcn_mfma_f32_16x16x32_bf16(pa, vb1, acc1, 0, 0, 0);
        }
    }
    // epilogue: row-sum lives in acc1 at d=24 (lane q==8 of each g-group)
    int src = (lane & 48) | 8;
#pragma unroll
    for (int j = 0; j < 4; ++j) {
      float ls = __shfl(acc1[j], src);
      float iv = 1.f / ls;
      int t_abs = t0 + w * 16 + g * 4 + j;
      long orow = (long)(b * T_ + t_abs) * C_ + hh * D_;
      o[orow + q] = f2b(acc0[j] * iv);
      if (q < 8) o[orow + 16 + q] = f2b(acc1[j] * iv);
    }
  }
}

// ---------------- host side ----------------
extern "C" void kernel_launch(void* const* d_in, const int* in_sizes, int n_in,
                              void* d_out, int out_size, void* d_ws, size_t ws_size,
                              hipStream_t stream) {
  (void)in_sizes; (void)n_in; (void)out_size; (void)ws_size;
  const float* idx  = (const float*)d_in[0];
  const float* pos  = (const float*)d_in[1];
  const float* Wq   = (const float*)d_in[2];
  const float* Wk   = (const float*)d_in[3];
  const float* Wv   = (const float*)d_in[4];
  const float* Wo   = (const float*)d_in[5];
  const float* bo   = (const float*)d_in[6];
  const float* ln1g = (const float*)d_in[7];
  const float* ln1b = (const float*)d_in[8];
  const float* ln2g = (const float*)d_in[9];
  const float* ln2b = (const float*)d_in[10];
  const float* W1   = (const float*)d_in[11];
  const float* b1   = (const float*)d_in[12];
  const float* W2   = (const float*)d_in[13];
  const float* b2   = (const float*)d_in[14];
  const float* lnfg = (const float*)d_in[15];
  const float* lnfb = (const float*)d_in[16];

  char* ws = (char*)d_ws;
  float*  x     = (float*)(ws);                 // 12,582,912 B
  ushort* h     = (ushort*)(ws + 12582912);     //  6,291,456 (LN out / attn out)
  ushort* Qp    = (ushort*)(ws + 18874368);     //  8,388,608  [128][1024][32]
  ushort* Kp    = (ushort*)(ws + 27262976);     //  8,388,608  [128][1024][32]
  ushort* Vt    = (ushort*)(ws + 35651584);     //  8,388,608  [128][32][1024]
  ushort* u     = (ushort*)(ws + 44040192);     // 25,165,824
  ushort* WqkvT = (ushort*)(ws + 69206016);     //  7,077,888
  ushort* WoT   = (ushort*)(ws + 76283904);     //  2,359,296
  ushort* W1T   = (ushort*)(ws + 78643200);     //  9,437,184
  ushort* W2T   = (ushort*)(ws + 88080384);     //  9,437,184  -> end 97,517,568

  hipMemsetAsync(Qp, 0, 25165824, stream);  // zero d-pads of Qp/Kp/Vt (persist)
  k_ones<<<128, 256, 0, stream>>>(Vt);      // Vt[bh][24][:] = 1.0 (row-sum trick)

  k_trans_qkv<<<dim3(1, 12, L_ * H_), 256, 0, stream>>>(Wq, WqkvT, 0);
  k_trans_qkv<<<dim3(1, 12, L_ * H_), 256, 0, stream>>>(Wk, WqkvT, 1);
  k_trans_qkv<<<dim3(1, 12, L_ * H_), 256, 0, stream>>>(Wv, WqkvT, 2);
  k_trans_w<<<dim3(12, 12, L_), 256, 0, stream>>>(Wo, WoT, C_, C_);
  k_trans_w<<<dim3(48, 12, L_), 256, 0, stream>>>(W1, W1T, C_, F_);
  k_trans_w<<<dim3(12, 48, L_), 256, 0, stream>>>(W2, W2T, F_, C_);

  k_embed<<<(M_ * C_) / (256 * 4), 256, 0, stream>>>(idx, pos, x);

  for (int l = 0; l < L_; ++l) {
    k_ln<<<M_ / 4, 256, 0, stream>>>(x, ln1g + l * C_, ln1b + l * C_, h);
    k_gemm<128><<<dim3(1152 / 128, M_ / 128), 256, 0, stream>>>(
        h, C_, WqkvT + (long)l * 1152 * C_, C_,
        nullptr, nullptr, nullptr, nullptr, Qp, Kp, Vt, 1152, C_, 0);
    k_attn<<<dim3(B_ * H_, 8), 256, 0, stream>>>(Qp, Kp, Vt, h);
    k_gemm<64><<<dim3(C_ / 64, M_ / 128), 256, 0, stream>>>(
        h, C_, WoT + (long)l * C_ * C_, C_,
        bo + l * C_, x, x, nullptr, nullptr, nullptr, nullptr, C_, C_, 0);
    k_ln<<<M_ / 4, 256, 0, stream>>>(x, ln2g + l * C_, ln2b + l * C_, h);
    k_gemm<128><<<dim3(F_ / 128, M_ / 128), 256, 0, stream>>>(
        h, C_, W1T + (long)l * F_ * C_, C_,
        b1 + l * F_, nullptr, nullptr, u, nullptr, nullptr, nullptr, F_, C_, 1);
    k_gemm<64><<<dim3(C_ / 64, M_ / 128), 256, 0, stream>>>(
        u, F_, W2T + (long)l * C_ * F_, F_,
        b2 + l * C_, x, x, nullptr, nullptr, nullptr, nullptr, C_, F_, 0);
  }
  k_lnf<<<M_ / 4, 256, 0, stream>>>(x, lnfg, lnfb, (float*)d_out);
}

// Round 9
// 1567.810 us; speedup vs baseline: 1.0026x; 1.0026x over previous
//
#include <hip/hip_runtime.h>

// ---- problem constants ----
#define B_ 8
#define T_ 1024
#define C_ 384
#define L_ 8
#define H_ 16
#define D_ 24
#define F_ 1536
#define M_ 8192   // B_*T_

using bf16x8 = __attribute__((ext_vector_type(8))) __bf16;
using f32x4  = __attribute__((ext_vector_type(4))) float;

__device__ __forceinline__ ushort f2b(float f) {
  union { float f; unsigned u; } cv; cv.f = f;
  unsigned u = cv.u;
  return (ushort)((u + 0x7FFFu + ((u >> 16) & 1u)) >> 16);  // RNE
}
__device__ __forceinline__ ushort f2b_cvt(float f) {  // 1-inst HW cvt (RNE)
  __bf16 h = (__bf16)f;
  return *(ushort*)&h;
}
__device__ __forceinline__ unsigned pk2(float a, float b) {  // 2 bf16 -> dword
  union { ushort2 s; unsigned u; } cv;
  cv.s.x = f2b_cvt(a); cv.s.y = f2b_cvt(b);
  return cv.u;
}
union U4 { uint4 u; bf16x8 v; };
__device__ __forceinline__ void gload_lds16(const void* g, void* l) {
  __builtin_amdgcn_global_load_lds((const __attribute__((address_space(1))) void*)g,
                                   (__attribute__((address_space(3))) void*)l, 16, 0, 0);
}

// Q pre-scale: 24^-0.5 * log2(e)  (softmax exp becomes bare exp2)
#define QSCL 0.29448870f

// ---------------- embed: x = idx + pos ----------------
__global__ __launch_bounds__(256) void k_embed(const float* __restrict__ idx,
                                               const float* __restrict__ pos,
                                               float* __restrict__ x) {
  long i4 = ((long)blockIdx.x * 256 + threadIdx.x) * 4;
  float4 a = *(const float4*)(idx + i4);
  long p = i4 % (long)(T_ * C_);
  float4 b = *(const float4*)(pos + p);
  a.x += b.x; a.y += b.y; a.z += b.z; a.w += b.w;
  *(float4*)(x + i4) = a;
}

// ---------------- layernorm (fp32 in) -> bf16 out ----------------
__global__ __launch_bounds__(256) void k_ln(const float* __restrict__ x,
                                            const float* __restrict__ g,
                                            const float* __restrict__ b,
                                            ushort* __restrict__ out) {
  int row  = blockIdx.x * 4 + (threadIdx.x >> 6);
  int lane = threadIdx.x & 63;
  const float* xr = x + (long)row * C_;
  float v[6]; float sum = 0.f;
#pragma unroll
  for (int i = 0; i < 3; ++i) {
    float2 t = *(const float2*)(xr + 2*(lane + 64*i));
    v[2*i] = t.x; v[2*i+1] = t.y; sum += t.x + t.y;
  }
#pragma unroll
  for (int m = 1; m < 64; m <<= 1) sum += __shfl_xor(sum, m);
  float mean = sum * (1.f / C_);
  float vs = 0.f;
#pragma unroll
  for (int i = 0; i < 6; ++i) { float d = v[i] - mean; vs += d * d; }
#pragma unroll
  for (int m = 1; m < 64; m <<= 1) vs += __shfl_xor(vs, m);
  float rstd = rsqrtf(vs * (1.f / C_) + 1e-5f);
  ushort* orow = out + (long)row * C_;
#pragma unroll
  for (int i = 0; i < 3; ++i) {
    int c = 2*(lane + 64*i);
    float2 gg = *(const float2*)(g + c);
    float2 bb = *(const float2*)(b + c);
    ushort2 w;
    w.x = f2b((v[2*i]   - mean) * rstd * gg.x + bb.x);
    w.y = f2b((v[2*i+1] - mean) * rstd * gg.y + bb.y);
    *(ushort2*)(orow + c) = w;
  }
}

// ---------------- final layernorm + relu -> fp32 d_out ----------------
__global__ __launch_bounds__(256) void k_lnf(const float* __restrict__ x,
                                             const float* __restrict__ g,
                                             const float* __restrict__ b,
                                             float* __restrict__ out) {
  int row  = blockIdx.x * 4 + (threadIdx.x >> 6);
  int lane = threadIdx.x & 63;
  const float* xr = x + (long)row * C_;
  float v[6]; float sum = 0.f;
#pragma unroll
  for (int i = 0; i < 3; ++i) {
    float2 t = *(const float2*)(xr + 2*(lane + 64*i));
    v[2*i] = t.x; v[2*i+1] = t.y; sum += t.x + t.y;
  }
#pragma unroll
  for (int m = 1; m < 64; m <<= 1) sum += __shfl_xor(sum, m);
  float mean = sum * (1.f / C_);
  float vs = 0.f;
#pragma unroll
  for (int i = 0; i < 6; ++i) { float d = v[i] - mean; vs += d * d; }
#pragma unroll
  for (int m = 1; m < 64; m <<= 1) vs += __shfl_xor(vs, m);
  float rstd = rsqrtf(vs * (1.f / C_) + 1e-5f);
  float* orow = out + (long)row * C_;
#pragma unroll
  for (int i = 0; i < 3; ++i) {
    int c = 2*(lane + 64*i);
    float2 gg = *(const float2*)(g + c);
    float2 bb = *(const float2*)(b + c);
    float2 w;
    w.x = fmaxf((v[2*i]   - mean) * rstd * gg.x + bb.x, 0.f);
    w.y = fmaxf((v[2*i+1] - mean) * rstd * gg.y + bb.y, 0.f);
    *(float2*)(orow + c) = w;
  }
}

// ---------------- weight transpose+cast kernels ----------------
__global__ __launch_bounds__(256) void k_trans_qkv(const float* __restrict__ src,
                                                   ushort* __restrict__ dst, int which) {
  __shared__ float tile[32][33];
  int z = blockIdx.z;            // l*H + h
  int l = z >> 4, hh = z & 15;
  const float* sb = src + (long)z * C_ * D_;
  ushort* db = dst + (long)l * (3*C_) * C_ + (long)(which * C_ + hh * D_) * C_;
  int r0 = blockIdx.y * 32;      // c dim
  int tx = threadIdx.x & 31, ty = threadIdx.x >> 5;
#pragma unroll
  for (int i = 0; i < 32; i += 8)
    tile[ty + i][tx] = (tx < D_) ? sb[(long)(r0 + ty + i) * D_ + tx] : 0.f;
  __syncthreads();
#pragma unroll
  for (int i = 0; i < 32; i += 8) {
    int s = ty + i, r = r0 + tx;
    if (s < D_) db[(long)s * C_ + r] = f2b(tile[tx][ty + i]);
  }
}

__global__ __launch_bounds__(256) void k_trans_w(const float* __restrict__ src,
                                                 ushort* __restrict__ dst, int R, int S) {
  __shared__ float tile[32][33];
  const float* sb = src + (long)blockIdx.z * R * S;
  ushort* db = dst + (long)blockIdx.z * R * S;
  int r0 = blockIdx.y * 32, s0 = blockIdx.x * 32;
  int tx = threadIdx.x & 31, ty = threadIdx.x >> 5;
#pragma unroll
  for (int i = 0; i < 32; i += 8) {
    int r = r0 + ty + i, s = s0 + tx;
    tile[ty + i][tx] = (r < R && s < S) ? sb[(long)r * S + s] : 0.f;
  }
  __syncthreads();
#pragma unroll
  for (int i = 0; i < 32; i += 8) {
    int s = s0 + ty + i, r = r0 + tx;
    if (s < S && r < R) db[(long)s * R + r] = f2b(tile[tx][ty + i]);
  }
}

// ---------------- ones row for Vt (d=24): PV then yields row-sums free ----
__global__ __launch_bounds__(256) void k_ones(ushort* __restrict__ Vt) {
  ushort4 one4 = {0x3F80, 0x3F80, 0x3F80, 0x3F80};
  *(ushort4*)(Vt + ((long)blockIdx.x * 32 + 24) * 1024 + threadIdx.x * 4) = one4;
}

// ---------------- GEMM: A[M,K]bf16 @ Bt[N,K]^T -> out[M,N] ----------------
// BMxBN tile, BK=64, 4 waves, mfma 16x16x32, global_load_lds(16B) with
// pre-swizzled SOURCE + XOR-swizzled READ (rule 21: linear LDS dest).
// QKV mode (qp!=null, BM=BN=128): epilogue scatters Q (pre-scaled) -> Qp,
// K -> Kp with v8 fragment-permuted rows, V -> Vt[bh][d][1024].
template<int BM, int BN>
__global__ __launch_bounds__(256) void k_gemm(const ushort* __restrict__ A, int lda,
                                              const ushort* __restrict__ Bt, int ldb,
                                              const float* __restrict__ bias,
                                              const float* resid,
                                              float* outF, ushort* outB,
                                              ushort* qp, ushort* kp, ushort* vt,
                                              int N, int K, int relu) {
  __shared__ ushort As[BM * 64];
  __shared__ ushort Bs[BN * 64];
  constexpr int ITA = BM / 32;                 // A-tile gload iters
  constexpr int ITB = BN / 32;                 // B-tile gload iters
  constexpr int MF_M = BM / 32;                // 2-wave split in M -> BM/2/16
  constexpr int MF_N = BN / 32;
  int m0 = blockIdx.y * BM, n0 = blockIdx.x * BN;
  int tid = threadIdx.x, lane = tid & 63, wid = tid >> 6;
  int wr = (wid >> 1) * (BM / 2);
  int wc = (wid & 1) * (BN / 2);
  int g = lane >> 4, q = lane & 15;
  f32x4 acc[MF_M][MF_N] = {};

  for (int k0 = 0; k0 < K; k0 += 64) {
    __syncthreads();
#pragma unroll
    for (int it = 0; it < ITA; ++it) {
      int idx = tid + it * 256;
      int r = idx >> 3;
      int ch = ((idx & 7) ^ (r & 7)) << 3;    // inverse-swizzled source chunk
      gload_lds16(A + (long)(m0 + r) * lda + k0 + ch,
                  (char*)As + (wid * 64 + it * 256) * 16);
    }
#pragma unroll
    for (int it = 0; it < ITB; ++it) {
      int idx = tid + it * 256;
      int r = idx >> 3;
      int ch = ((idx & 7) ^ (r & 7)) << 3;
      gload_lds16(Bt + (long)(n0 + r) * ldb + k0 + ch,
                  (char*)Bs + (wid * 64 + it * 256) * 16);
    }
    __syncthreads();   // compiler drains vmcnt before s_barrier
#pragma unroll
    for (int kk = 0; kk < 2; ++kk) {
      bf16x8 af[MF_M], bfr[MF_N];
#pragma unroll
      for (int mi = 0; mi < MF_M; ++mi) {
        int row = wr + mi * 16 + q;
        int byt = ((row * 64 + kk * 32 + g * 8) * 2) ^ ((row & 7) << 4);
        af[mi] = *(const bf16x8*)((const char*)As + byt);
      }
#pragma unroll
      for (int ni = 0; ni < MF_N; ++ni) {
        int row = wc + ni * 16 + q;
        int byt = ((row * 64 + kk * 32 + g * 8) * 2) ^ ((row & 7) << 4);
        bfr[ni] = *(const bf16x8*)((const char*)Bs + byt);
      }
#pragma unroll
      for (int mi = 0; mi < MF_M; ++mi)
#pragma unroll
        for (int ni = 0; ni < MF_N; ++ni)
          acc[mi][ni] = __builtin_amdgcn_mfma_f32_16x16x32_bf16(af[mi], bfr[ni], acc[mi][ni], 0, 0, 0);
    }
  }
  // epilogue: D layout col=lane&15, row=4*(lane>>4)+j  [m89-verified]
#pragma unroll
  for (int mi = 0; mi < MF_M; ++mi)
#pragma unroll
    for (int ni = 0; ni < MF_N; ++ni) {
      int rb = m0 + wr + mi * 16 + g * 4;
      int cc = n0 + wc + ni * 16 + q;
      float bv = bias ? bias[cc] : 0.f;
      float vals[4];
#pragma unroll
      for (int j = 0; j < 4; ++j) {
        float val = acc[mi][ni][j] + bv;
        if (resid) val += resid[(long)(rb + j) * N + cc];
        if (relu)  val = fmaxf(val, 0.f);
        vals[j] = val;
      }
      if (qp) {
        // QKV routing (wave-uniform branch: 16-col windows never straddle 384s)
        int sec = (cc >= 768) ? 2 : ((cc >= 384) ? 1 : 0);
        int col = cc - sec * 384;
        int hd = (col * 43691) >> 20;         // /24
        int dd = col - hd * 24;
        int bb = rb >> 10, tt = rb & 1023;
        int bh = bb * 16 + hd;
        if (sec == 2) {
          ushort4 w4 = { f2b(vals[0]), f2b(vals[1]), f2b(vals[2]), f2b(vals[3]) };
          *(ushort4*)(vt + ((long)bh * 32 + dd) * 1024 + tt) = w4;
        } else {
          float sfac = sec ? 1.f : QSCL;      // pre-scale Q for exp2 softmax
          int tts = tt;
          // K rows permuted within each 128-row block so attn v8 P-fragments
          // are lane-local: bits g,g,b,j,j -> b,g,g,j,j
          if (sec) tts = (tt & ~31) | ((tt & 4) << 2) | ((tt & 24) >> 1) | (tt & 3);
          ushort* dst = (sec ? kp : qp) + ((long)bh * 1024 + tts) * 32 + dd;
#pragma unroll
          for (int j = 0; j < 4; ++j) dst[j * 32] = f2b(vals[j] * sfac);
        }
      } else {
#pragma unroll
        for (int j = 0; j < 4; ++j) {
          long off = (long)(rb + j) * N + cc;
          if (outF) outF[off] = vals[j];
          if (outB) outB[off] = f2b(vals[j]);
        }
      }
    }
}

// ---------------- flash attention v8: in-register P, zero LDS ----------------
// Swapped QK (mfma(kb,qa)) + permuted Kp rows => lane (g,q) accumulates its PV
// A-fragment pa[kk] (s = kk*32+8g+0..7 for q-row t=q) entirely in registers:
// no P LDS bounce, no cross-lane. Balanced 2-pass blocks (9 tiles each),
// K depth-1 prefetch, diagonal-only masking, exp2 softmax, ones-row row-sum.
__global__ __launch_bounds__(256) void k_attn(const ushort* __restrict__ Qp,
                                              const ushort* __restrict__ Kp,
                                              const ushort* __restrict__ Vt,
                                              ushort* __restrict__ o) {
  int bh = blockIdx.x, by = blockIdx.y;
  int b = bh >> 4, hh = bh & 15;
  int tid = threadIdx.x, lane = tid & 63, w = tid >> 6;
  int g = lane >> 4, q = lane & 15;
  const f32x4 zf = {0.f, 0.f, 0.f, 0.f};

  const ushort* qb  = Qp + (long)bh * 1024 * 32;
  const ushort* kb_ = Kp + (long)bh * 1024 * 32;
  const ushort* vtb = Vt + (long)bh * 32 * 1024;

#pragma unroll
  for (int pass = 0; pass < 2; ++pass) {
    int t0 = (pass ? (15 - by) : by) * 64;
    int send = t0 + 64;
    int nT = (send + 127) >> 7;

    bf16x8 qa = *(const bf16x8*)(qb + (t0 + w * 16 + q) * 32 + g * 8);
    f32x4 acc0 = zf, acc1 = zf;

    bf16x8 kf[8];
#pragma unroll
    for (int si = 0; si < 8; ++si)
      kf[si] = *(const bf16x8*)(kb_ + (si * 16 + q) * 32 + g * 8);

    // interior tiles: fully below diagonal -> no causal mask needed
    for (int it = 0; it < nT - 1; ++it) {
      int s0 = it << 7;
      uint4 pa[4];
      {
        f32x4 sc[4];
#pragma unroll
        for (int si = 0; si < 4; ++si)
          sc[si] = __builtin_amdgcn_mfma_f32_16x16x32_bf16(kf[si], qa, zf, 0, 0, 0);
#pragma unroll
        for (int si = 0; si < 4; ++si)   // prefetch next tile's K (low half)
          kf[si] = *(const bf16x8*)(kb_ + (s0 + 128 + si * 16 + q) * 32 + g * 8);
#pragma unroll
        for (int si = 0; si < 4; ++si) {
          unsigned d0 = pk2(exp2f(sc[si][0]), exp2f(sc[si][1]));
          unsigned d1 = pk2(exp2f(sc[si][2]), exp2f(sc[si][3]));
          if ((si & 1) == 0) { pa[si >> 1].x = d0; pa[si >> 1].y = d1; }
          else               { pa[si >> 1].z = d0; pa[si >> 1].w = d1; }
        }
      }
      {
        f32x4 sc[4];
#pragma unroll
        for (int si = 0; si < 4; ++si)
          sc[si] = __builtin_amdgcn_mfma_f32_16x16x32_bf16(kf[si + 4], qa, zf, 0, 0, 0);
#pragma unroll
        for (int si = 0; si < 4; ++si)   // prefetch next tile's K (high half)
          kf[si + 4] = *(const bf16x8*)(kb_ + (s0 + 128 + (si + 4) * 16 + q) * 32 + g * 8);
#pragma unroll
        for (int si = 0; si < 4; ++si) {
          unsigned d0 = pk2(exp2f(sc[si][0]), exp2f(sc[si][1]));
          unsigned d1 = pk2(exp2f(sc[si][2]), exp2f(sc[si][3]));
          if ((si & 1) == 0) { pa[2 + (si >> 1)].x = d0; pa[2 + (si >> 1)].y = d1; }
          else               { pa[2 + (si >> 1)].z = d0; pa[2 + (si >> 1)].w = d1; }
        }
      }
#pragma unroll
      for (int kk = 0; kk < 4; ++kk) {
        U4 t; t.u = pa[kk];
        bf16x8 vb0 = *(const bf16x8*)(vtb + (long)q * 1024 + s0 + kk * 32 + g * 8);
        acc0 = __builtin_amdgcn_mfma_f32_16x16x32_bf16(t.v, vb0, acc0, 0, 0, 0);
        bf16x8 vb1 = *(const bf16x8*)(vtb + (long)(16 + q) * 1024 + s0 + kk * 32 + g * 8);
        acc1 = __builtin_amdgcn_mfma_f32_16x16x32_bf16(t.v, vb1, acc1, 0, 0, 0);
      }
    }
    // diagonal tile (masked on s per lane/elem)
    {
      int s0 = (nT - 1) << 7;
      int rem = send - s0;                 // 64 or 128
      int siMax = rem >> 4, kkMax = rem >> 5;
      uint4 pa[4];
      f32x4 sc[8];
#pragma unroll
      for (int si = 0; si < 8; ++si)
        if (si < siMax)
          sc[si] = __builtin_amdgcn_mfma_f32_16x16x32_bf16(kf[si], qa, zf, 0, 0, 0);
      int t_abs = t0 + w * 16 + q;
#pragma unroll
      for (int si = 0; si < 8; ++si)
        if (si < siMax) {
          int sb = s0 + ((si >> 1) << 5) + ((si & 1) << 2) + (g << 3);
          float p0 = (sb + 0 <= t_abs) ? exp2f(sc[si][0]) : 0.f;
          float p1 = (sb + 1 <= t_abs) ? exp2f(sc[si][1]) : 0.f;
          float p2 = (sb + 2 <= t_abs) ? exp2f(sc[si][2]) : 0.f;
          float p3 = (sb + 3 <= t_abs) ? exp2f(sc[si][3]) : 0.f;
          unsigned d0 = pk2(p0, p1), d1 = pk2(p2, p3);
          if ((si & 1) == 0) { pa[si >> 1].x = d0; pa[si >> 1].y = d1; }
          else               { pa[si >> 1].z = d0; pa[si >> 1].w = d1; }
        }
#pragma unroll
      for (int kk = 0; kk < 4; ++kk)
        if (kk < kkMax) {
          U4 t; t.u = pa[kk];
          bf16x8 vb0 = *(const bf16x8*)(vtb + (long)q * 1024 + s0 + kk * 32 + g * 8);
          acc0 = __builtin_amdgcn_mfma_f32_16x16x32_bf16(t.v, vb0, acc0, 0, 0, 0);
          bf16x8 vb1 = *(const bf16x8*)(vtb + (long)(16 + q) * 1024 + s0 + kk * 32 + g * 8);
          acc1 = __builtin_amdgcn_mfma_f32_16x16x32_bf16(t.v, vb1, acc1, 0, 0, 0);
        }
    }
    // epilogue: row-sum lives in acc1 at d=24 (lane q==8 of each g-group)
    int src = (lane & 48) | 8;
#pragma unroll
    for (int j = 0; j < 4; ++j) {
      float ls = __shfl(acc1[j], src);
      float iv = 1.f / ls;
      int t_abs = t0 + w * 16 + g * 4 + j;
      long orow = (long)(b * T_ + t_abs) * C_ + hh * D_;
      o[orow + q] = f2b(acc0[j] * iv);
      if (q < 8) o[orow + 16 + q] = f2b(acc1[j] * iv);
    }
  }
}

// ---------------- host side ----------------
extern "C" void kernel_launch(void* const* d_in, const int* in_sizes, int n_in,
                              void* d_out, int out_size, void* d_ws, size_t ws_size,
                              hipStream_t stream) {
  (void)in_sizes; (void)n_in; (void)out_size; (void)ws_size;
  const float* idx  = (const float*)d_in[0];
  const float* pos  = (const float*)d_in[1];
  const float* Wq   = (const float*)d_in[2];
  const float* Wk   = (const float*)d_in[3];
  const float* Wv   = (const float*)d_in[4];
  const float* Wo   = (const float*)d_in[5];
  const float* bo   = (const float*)d_in[6];
  const float* ln1g = (const float*)d_in[7];
  const float* ln1b = (const float*)d_in[8];
  const float* ln2g = (const float*)d_in[9];
  const float* ln2b = (const float*)d_in[10];
  const float* W1   = (const float*)d_in[11];
  const float* b1   = (const float*)d_in[12];
  const float* W2   = (const float*)d_in[13];
  const float* b2   = (const float*)d_in[14];
  const float* lnfg = (const float*)d_in[15];
  const float* lnfb = (const float*)d_in[16];

  char* ws = (char*)d_ws;
  float*  x     = (float*)(ws);                 // 12,582,912 B
  ushort* h     = (ushort*)(ws + 12582912);     //  6,291,456 (LN out / attn out)
  ushort* Qp    = (ushort*)(ws + 18874368);     //  8,388,608  [128][1024][32]
  ushort* Kp    = (ushort*)(ws + 27262976);     //  8,388,608  [128][1024][32] (row-permuted)
  ushort* Vt    = (ushort*)(ws + 35651584);     //  8,388,608  [128][32][1024]
  ushort* u     = (ushort*)(ws + 44040192);     // 25,165,824
  ushort* WqkvT = (ushort*)(ws + 69206016);     //  7,077,888
  ushort* WoT   = (ushort*)(ws + 76283904);     //  2,359,296
  ushort* W1T   = (ushort*)(ws + 78643200);     //  9,437,184
  ushort* W2T   = (ushort*)(ws + 88080384);     //  9,437,184  -> end 97,517,568

  hipMemsetAsync(Qp, 0, 25165824, stream);  // zero d-pads of Qp/Kp/Vt (persist)
  k_ones<<<128, 256, 0, stream>>>(Vt);      // Vt[bh][24][:] = 1.0 (row-sum trick)

  k_trans_qkv<<<dim3(1, 12, L_ * H_), 256, 0, stream>>>(Wq, WqkvT, 0);
  k_trans_qkv<<<dim3(1, 12, L_ * H_), 256, 0, stream>>>(Wk, WqkvT, 1);
  k_trans_qkv<<<dim3(1, 12, L_ * H_), 256, 0, stream>>>(Wv, WqkvT, 2);
  k_trans_w<<<dim3(12, 12, L_), 256, 0, stream>>>(Wo, WoT, C_, C_);
  k_trans_w<<<dim3(48, 12, L_), 256, 0, stream>>>(W1, W1T, C_, F_);
  k_trans_w<<<dim3(12, 48, L_), 256, 0, stream>>>(W2, W2T, F_, C_);

  k_embed<<<(M_ * C_) / (256 * 4), 256, 0, stream>>>(idx, pos, x);

  for (int l = 0; l < L_; ++l) {
    k_ln<<<M_ / 4, 256, 0, stream>>>(x, ln1g + l * C_, ln1b + l * C_, h);
    k_gemm<128,128><<<dim3(1152 / 128, M_ / 128), 256, 0, stream>>>(
        h, C_, WqkvT + (long)l * 1152 * C_, C_,
        nullptr, nullptr, nullptr, nullptr, Qp, Kp, Vt, 1152, C_, 0);
    k_attn<<<dim3(B_ * H_, 8), 256, 0, stream>>>(Qp, Kp, Vt, h);
    k_gemm<64,64><<<dim3(C_ / 64, M_ / 64), 256, 0, stream>>>(
        h, C_, WoT + (long)l * C_ * C_, C_,
        bo + l * C_, x, x, nullptr, nullptr, nullptr, nullptr, C_, C_, 0);
    k_ln<<<M_ / 4, 256, 0, stream>>>(x, ln2g + l * C_, ln2b + l * C_, h);
    k_gemm<128,128><<<dim3(F_ / 128, M_ / 128), 256, 0, stream>>>(
        h, C_, W1T + (long)l * F_ * C_, C_,
        b1 + l * F_, nullptr, nullptr, u, nullptr, nullptr, nullptr, F_, C_, 1);
    k_gemm<64,64><<<dim3(C_ / 64, M_ / 64), 256, 0, stream>>>(
        u, F_, W2T + (long)l * C_ * F_, F_,
        b2 + l * C_, x, x, nullptr, nullptr, nullptr, nullptr, C_, F_, 0);
  }
  k_lnf<<<M_ / 4, 256, 0, stream>>>(x, lnfg, lnfb, (float*)d_out);
}